// Round 2
// baseline (3829.914 us; speedup 1.0000x reference)
//
#include <hip/hip_runtime.h>
#include <hip/hip_bf16.h>
#include <math.h>

// Encoder_DRNN: emb gather -> 3 dilated GRU layers (rates 1,2,4) -> masked out.
// Batch sort/unsort in the reference is a mathematical no-op (shared weights,
// no packing) and is skipped. Time-major [T,B,H] storage makes every dilated
// step a contiguous row slab: hd[tp][d] == h[(tp*rate + d/B)][d%B].
//
// Sizes: B=4096 T=50 E=H=128 G=3H=384. Layer l: rate=2^l, Bd=rate*B,
// steps ceil(50/rate) (T padded to 52 for layer 2).
//
// ws layout (floats):
//   A: 52*4096*128 = 27,262,976 (time-major activations, ping)
//   3 x [wihP(49152) whhP(49152) bias(512)]
//   mask: 4096
// d_out (50*4096*128 floats) doubles as the pong buffer.

#define B_N 4096
#define T_N 50
#define H_N 128
#define G_N 384
#define TP2 52

// ---- weight prep: packed layout [k4(32)][gate(3)][c(128)][kk(4)] ----
// float4 view index: k4*384 + gate*128 + c
__global__ void prep_weights_kernel(const float* __restrict__ Wih,
                                    const float* __restrict__ Whh,
                                    const float* __restrict__ bih,
                                    const float* __restrict__ bhh,
                                    float* __restrict__ wihP,
                                    float* __restrict__ whhP,
                                    float* __restrict__ bias) {
  const int g    = blockIdx.x;      // 0..383
  const int gate = g >> 7;          // 0..2
  const int c    = g & 127;
  const int k    = threadIdx.x;     // 0..127
  const int idx  = ((k >> 2) * 3 + gate) * 512 + c * 4 + (k & 3);
  wihP[idx] = Wih[(size_t)g * H_N + k];
  whhP[idx] = Whh[(size_t)g * H_N + k];
  if (k == 0) {
    // bias: [0,256)=bih+bhh (r,z); [256,384)=bih_n; [384,512)=bhh_n
    if (g < 256) bias[g] = bih[g] + bhh[g];
    else { bias[g] = bih[g]; bias[g + 128] = bhh[g]; }
  }
}

// ---- embedding gather -> time-major [T,B,E] ----
__global__ void gather_emb_kernel(const int* __restrict__ tok,
                                  const float* __restrict__ emb,
                                  float* __restrict__ X) {
  const int t  = blockIdx.x >> 9;          // 0..49
  const int b0 = (blockIdx.x & 511) << 3;  // 8 batch rows per block
  const int bi = threadIdx.x >> 5;
  const int cc = threadIdx.x & 31;         // float4 chunk of 128-wide row
  const int b  = b0 + bi;
  const int tk = tok[b * T_N + t];
  float4 v = ((const float4*)emb)[(size_t)tk * 32 + cc];
  ((float4*)X)[((size_t)t * B_N + b) * 32 + cc] = v;
}

// ---- sentence mask: 1.0 iff any token > 0 ----
__global__ void mask_kernel(const int* __restrict__ tok, float* __restrict__ mask) {
  const int b = blockIdx.x * 256 + threadIdx.x;
  int any = 0;
  for (int t = 0; t < T_N; ++t) any |= tok[b * T_N + t];
  mask[b] = any ? 1.0f : 0.0f;
}

// ---- fused GRU layer, persistent over time steps ----
// 256 threads: c0 = tid&127 (one channel each), 2 row-groups x RPT rows.
// h lives in LDS [R][128] fp32; weights stream k4-packed from L1/L2.
__device__ __forceinline__ float sigm(float x) {
  return 1.0f / (1.0f + __expf(-x));
}
__device__ __forceinline__ float tanh_fast(float x) {
  x = fminf(fmaxf(x, -15.0f), 15.0f);   // tanh(+-15)==+-1 in fp32
  const float t = __expf(2.0f * x);
  return (t - 1.0f) / (t + 1.0f);
}
__device__ __forceinline__ float dot4_acc(float s, float4 a, float4 b) {
  s = fmaf(a.x, b.x, s); s = fmaf(a.y, b.y, s);
  s = fmaf(a.z, b.z, s); s = fmaf(a.w, b.w, s);
  return s;
}

template <int RPT, int RATE, int TSTEPS, bool LAST>
__global__ __launch_bounds__(256, 2) void gru_kernel(
    const float* __restrict__ X, float* __restrict__ Y,
    const float* __restrict__ wihP, const float* __restrict__ whhP,
    const float* __restrict__ bias, const float* __restrict__ mask) {
  constexpr int R = 2 * RPT;           // rows per block (2 row-groups)
  __shared__ float h_lds[R][H_N];

  const int tid = threadIdx.x;
  const int c0  = tid & 127;           // channel owned by this thread
  const int r0  = (tid >> 7) * RPT;    // row-group base (wave-uniform)
  const int d0  = blockIdx.x * R;      // dilated-row base of this block

  for (int i = tid; i < R * H_N / 4; i += 256)
    ((float4*)h_lds)[i] = make_float4(0.f, 0.f, 0.f, 0.f);

  const float br = bias[c0],       bz = bias[128 + c0];
  const float bi = bias[256 + c0], bh = bias[384 + c0];
  const float4* __restrict__ wv = (const float4*)wihP;
  const float4* __restrict__ uv = (const float4*)whhP;
  __syncthreads();

  for (int tp = 0; tp < TSTEPS; ++tp) {
    float s_r[RPT] = {}, s_z[RPT] = {}, s_i[RPT] = {}, s_h[RPT] = {};
    const float* xb = X + ((size_t)tp * RATE * B_N + d0 + r0) * H_N;

#pragma unroll 2
    for (int k4 = 0; k4 < 32; ++k4) {
      const float4 wr = wv[k4 * 384 + c0];
      const float4 wz = wv[k4 * 384 + 128 + c0];
      const float4 wn = wv[k4 * 384 + 256 + c0];
      const float4 ur = uv[k4 * 384 + c0];
      const float4 uz = uv[k4 * 384 + 128 + c0];
      const float4 un = uv[k4 * 384 + 256 + c0];
#pragma unroll
      for (int i = 0; i < RPT; ++i) {
        const float4 xv = *(const float4*)(xb + (size_t)i * H_N + k4 * 4);
        const float4 hv = *(const float4*)(&h_lds[r0 + i][k4 * 4]);
        s_r[i] = dot4_acc(dot4_acc(s_r[i], xv, wr), hv, ur);
        s_z[i] = dot4_acc(dot4_acc(s_z[i], xv, wz), hv, uz);
        s_i[i] = dot4_acc(s_i[i], xv, wn);
        s_h[i] = dot4_acc(s_h[i], hv, un);
      }
    }

    __syncthreads();  // all K-loop reads of h_lds done before updates

#pragma unroll
    for (int i = 0; i < RPT; ++i) {
      const int rl = r0 + i;
      const int d  = d0 + rl;
      const float hp = h_lds[rl][c0];
      const float rr = sigm(s_r[i] + br);
      const float zz = sigm(s_z[i] + bz);
      const float nn = tanh_fast(s_i[i] + bi + rr * (s_h[i] + bh));
      const float o  = (1.0f - zz) * nn + zz * hp;
      h_lds[rl][c0] = o;
      if (!LAST) {
        Y[((size_t)tp * RATE * B_N + d) * H_N + c0] = o;
      } else {
        const int b  = d & (B_N - 1);
        const int jj = d >> 12;              // sub-sequence index
        const int t  = tp * RATE + jj;
        if (t < T_N)
          Y[((size_t)b * T_N + t) * H_N + c0] = o * mask[b];
      }
    }
    __syncthreads();  // h_lds fully updated before next step
  }
}

// ---- launcher ----
extern "C" void kernel_launch(void* const* d_in, const int* in_sizes, int n_in,
                              void* d_out, int out_size, void* d_ws, size_t ws_size,
                              hipStream_t stream) {
  (void)in_sizes; (void)n_in; (void)out_size; (void)ws_size;
  const int*   tok = (const int*)d_in[0];
  const float* emb = (const float*)d_in[3];

  float* ws = (float*)d_ws;
  float* A  = ws;                                   // [52,4096,128]
  const size_t A_FLOATS = (size_t)TP2 * B_N * H_N;
  const size_t WSTRIDE  = (size_t)49152 * 2 + 512;
  float* warea = ws + A_FLOATS;
  float* maskp = warea + 3 * WSTRIDE;
  float* Bbuf  = (float*)d_out;                     // pong (50*4096*128)

  for (int l = 0; l < 3; ++l) {
    const float* Wih = (const float*)d_in[4 + 4 * l];
    const float* Whh = (const float*)d_in[5 + 4 * l];
    const float* bih = (const float*)d_in[6 + 4 * l];
    const float* bhh = (const float*)d_in[7 + 4 * l];
    float* wP = warea + l * WSTRIDE;
    prep_weights_kernel<<<G_N, H_N, 0, stream>>>(Wih, Whh, bih, bhh,
                                                 wP, wP + 49152, wP + 98304);
  }
  gather_emb_kernel<<<T_N * 512, 256, 0, stream>>>(tok, emb, A);
  mask_kernel<<<B_N / 256, 256, 0, stream>>>(tok, maskp);
  hipMemsetAsync(A + (size_t)T_N * B_N * H_N, 0,
                 (size_t)(TP2 - T_N) * B_N * H_N * sizeof(float), stream);

  float* w0 = warea;
  float* w1 = warea + WSTRIDE;
  float* w2 = warea + 2 * WSTRIDE;

  // layer 0: rate 1, 50 steps, Bd=4096,  256 blocks : A -> Bbuf
  gru_kernel<8, 1, 50, false><<<256, 256, 0, stream>>>(
      A, Bbuf, w0, w0 + 49152, w0 + 98304, maskp);
  // layer 1: rate 2, 25 steps, Bd=8192,  512 blocks : Bbuf -> A
  gru_kernel<8, 2, 25, false><<<512, 256, 0, stream>>>(
      Bbuf, A, w1, w1 + 49152, w1 + 98304, maskp);
  // layer 2: rate 4, 13 steps, Bd=16384, 1024 blocks: A -> d_out (masked)
  gru_kernel<8, 4, 13, true><<<1024, 256, 0, stream>>>(
      A, (float*)d_out, w2, w2 + 49152, w2 + 98304, maskp);
}

// Round 3
// 464.145 us; speedup vs baseline: 8.2515x; 8.2515x over previous
//
#include <hip/hip_runtime.h>
#include <hip/hip_bf16.h>
#include <hip/hip_fp16.h>
#include <math.h>

// Encoder_DRNN via fp16 MFMA.
// emb gather -> 3 dilated GRU layers (rates 1,2,4) -> masked fp32 out.
// Batch sort/unsort in the reference is a mathematical no-op (shared weights,
// no packing) -> skipped. Time-major [T,B,H] storage makes every dilated step
// a contiguous 16-row slab: dilated row d at step tp == time-major row
// tp*rate*B + d. So each layer is a chain of [rows x 128] @ [128 x 384] GEMMs.
//
// Per-layer kernel: grid = Bd/16 blocks x 512 thr (8 waves).
//   - Each wave owns 16 h-columns across the 3 gates (r,z,n).
//   - Weights (Wih+Whh) live in VGPRs as 24 preloaded B-fragments.
//   - h state lives in LDS (fp16, double-buffered, padded stride 136).
//   - x streamed from global per step with a 1-step register prefetch.
//   - 24 x v_mfma_f32_16x16x32_f16 per wave per step; fp32 accumulators.
// MFMA fragment maps (m89-verified C/D; canonical A/B):
//   A (MxK): lane holds A[lane&15][kc*32 + (lane>>4)*8 + j], j=0..7
//   B (KxN) from row-major [N][K]: lane holds W[n0+(lane&15)][same k]
//   C/D:     col = lane&15, row = (lane>>4)*4 + reg
//
// ws layout (bytes):
//   X0 fp16 [212992][128]  (54,525,952)   ping (layer0 in, layer1 out + pad)
//   X1 fp16 [212992][128]  (54,525,952)   pong (layer0 out, layer1 in)
//   Wp  fp16 3 x [2][384][128] (3 x 196,608)
//   biasP f32 3 x [512]    (r: bih+bhh | z: bih+bhh | bih_n | bhh_n)
//   maskF f32 [4096]

#define B_N 4096
#define T_N 50
#define H_N 128

typedef _Float16 half8 __attribute__((ext_vector_type(8)));
typedef float f32x4 __attribute__((ext_vector_type(4)));

// ---- weight prep: fp32 [384][128] -> fp16 same layout (N x K), bias combine --
__global__ void prep_weights_kernel(const float* __restrict__ Wih,
                                    const float* __restrict__ Whh,
                                    const float* __restrict__ bih,
                                    const float* __restrict__ bhh,
                                    _Float16* __restrict__ Wp,
                                    float* __restrict__ biasP) {
  const int g = blockIdx.x;      // 0..383
  const int k = threadIdx.x;     // 0..127
  Wp[g * H_N + k]         = (_Float16)Wih[(size_t)g * H_N + k];
  Wp[49152 + g * H_N + k] = (_Float16)Whh[(size_t)g * H_N + k];
  if (k == 0) {
    if (g < 256) biasP[g] = bih[g] + bhh[g];        // r,z: sums fold
    else { biasP[g] = bih[g]; biasP[g + 128] = bhh[g]; }  // n: keep split
  }
}

// ---- embedding gather -> time-major fp16 [T*B][128] ----
__global__ void gather_kernel(const int* __restrict__ tok,
                              const float* __restrict__ emb,
                              _Float16* __restrict__ X0) {
  const int tid = threadIdx.x;
  const int r   = blockIdx.x * 16 + (tid >> 4);   // time-major row, < 204800
  const int t   = r >> 12;
  const int b   = r & (B_N - 1);
  const int c8  = (tid & 15) * 8;
  const int tk  = tok[b * T_N + t];
  const float4* ep = (const float4*)(emb + (size_t)tk * H_N + c8);
  const float4 a = ep[0], d = ep[1];
  half8 v = { (_Float16)a.x, (_Float16)a.y, (_Float16)a.z, (_Float16)a.w,
              (_Float16)d.x, (_Float16)d.y, (_Float16)d.z, (_Float16)d.w };
  *(half8*)(X0 + (size_t)r * H_N + c8) = v;
}

// ---- sentence mask: 1.0 iff any token nonzero ----
__global__ void mask_kernel(const int* __restrict__ tok, float* __restrict__ mask) {
  const int b = blockIdx.x * 256 + threadIdx.x;
  int any = 0;
  for (int t = 0; t < T_N; ++t) any |= tok[b * T_N + t];
  mask[b] = any ? 1.0f : 0.0f;
}

__device__ __forceinline__ float sigm(float x) {
  return 1.0f / (1.0f + __expf(-x));
}
__device__ __forceinline__ float tanh_fast(float x) {
  x = fminf(fmaxf(x, -15.0f), 15.0f);
  const float t = __expf(2.0f * x);
  return (t - 1.0f) / (t + 1.0f);
}

// ---- fused GRU layer: x-GEMM + h-GEMM via MFMA, persistent over steps ----
template <int RATE, int TSTEPS, bool LAST>
__global__ __launch_bounds__(512, 2) void gru_mfma_kernel(
    const _Float16* __restrict__ X, void* __restrict__ Yv,
    const _Float16* __restrict__ Wp, const float* __restrict__ biasP,
    const float* __restrict__ maskF) {
  __shared__ _Float16 hs[2][16][136];   // padded stride vs 128: bank spread

  const int tid  = threadIdx.x;
  const int lane = tid & 63;
  const int w    = tid >> 6;            // wave 0..7
  const int cb   = w * 16;              // h-column base of this wave
  const int l15  = lane & 15;
  const int lq   = lane >> 4;           // 0..3
  const int c    = cb + l15;            // this lane's column (C-layout col)

  { // zero-init hs[0]
    _Float16* hp = &hs[0][0][0];
    for (int i = tid; i < 16 * 136; i += 512) hp[i] = (_Float16)0.f;
  }

  // preload 24 weight B-fragments into VGPRs (held across all steps)
  half8 Wf[3][4], Uf[3][4];
#pragma unroll
  for (int g = 0; g < 3; ++g)
#pragma unroll
    for (int kc = 0; kc < 4; ++kc) {
      const size_t off = (size_t)(g * H_N + c) * H_N + kc * 32 + lq * 8;
      Wf[g][kc] = *(const half8*)(Wp + off);
      Uf[g][kc] = *(const half8*)(Wp + 49152 + off);
    }

  const float br = biasP[c],       bz = biasP[128 + c];
  const float bi = biasP[256 + c], bh = biasP[384 + c];
  float hold[4] = {0.f, 0.f, 0.f, 0.f};   // own C-layout cells, reg-resident

  const int d0 = blockIdx.x * 16;

  half8 xc[4], xn[4];
  { // prefetch x for tp=0
    const _Float16* xp = X + ((size_t)d0 + l15) * H_N + lq * 8;
#pragma unroll
    for (int kc = 0; kc < 4; ++kc) xc[kc] = *(const half8*)(xp + kc * 32);
  }
  __syncthreads();

  for (int tp = 0; tp < TSTEPS; ++tp) {
    const int cur = tp & 1, nxt = cur ^ 1;

    { // prefetch next step's x (clamped re-read on last step)
      const int tn = (tp + 1 < TSTEPS) ? tp + 1 : tp;
      const _Float16* xp =
          X + ((size_t)tn * RATE * B_N + d0 + l15) * H_N + lq * 8;
#pragma unroll
      for (int kc = 0; kc < 4; ++kc) xn[kc] = *(const half8*)(xp + kc * 32);
    }

    half8 hf[4];   // A-fragments of h from LDS
#pragma unroll
    for (int kc = 0; kc < 4; ++kc)
      hf[kc] = *(const half8*)(&hs[cur][l15][kc * 32 + lq * 8]);

    f32x4 ar  = {br, br, br, br}, az  = {bz, bz, bz, bz};
    f32x4 ani = {bi, bi, bi, bi}, anh = {bh, bh, bh, bh};
#pragma unroll
    for (int kc = 0; kc < 4; ++kc) {
      ar  = __builtin_amdgcn_mfma_f32_16x16x32_f16(xc[kc], Wf[0][kc], ar,  0, 0, 0);
      az  = __builtin_amdgcn_mfma_f32_16x16x32_f16(xc[kc], Wf[1][kc], az,  0, 0, 0);
      ani = __builtin_amdgcn_mfma_f32_16x16x32_f16(xc[kc], Wf[2][kc], ani, 0, 0, 0);
      ar  = __builtin_amdgcn_mfma_f32_16x16x32_f16(hf[kc], Uf[0][kc], ar,  0, 0, 0);
      az  = __builtin_amdgcn_mfma_f32_16x16x32_f16(hf[kc], Uf[1][kc], az,  0, 0, 0);
      anh = __builtin_amdgcn_mfma_f32_16x16x32_f16(hf[kc], Uf[2][kc], anh, 0, 0, 0);
    }

#pragma unroll
    for (int j = 0; j < 4; ++j) {
      const int crow = lq * 4 + j;           // C-layout row
      const float rr = sigm(ar[j]);
      const float zz = sigm(az[j]);
      const float nn = tanh_fast(ani[j] + rr * anh[j]);
      const float hv = nn + zz * (hold[j] - nn);
      hold[j] = hv;

      // pack (even col, odd col) pair across lane^1 -> one b32 write
      const _Float16 hhalf = (_Float16)hv;
      const unsigned short hb = __builtin_bit_cast(unsigned short, hhalf);
      const unsigned int other =
          (unsigned short)__shfl_xor((int)hb, 1, 64);
      const unsigned int packed = (unsigned int)hb | (other << 16);

      if (!(lane & 1))
        *(unsigned int*)(&hs[nxt][crow][c]) = packed;   // c even here

      if (!LAST) {
        if (!(lane & 1)) {
          const size_t row_g = (size_t)tp * RATE * B_N + d0 + crow;
          *(unsigned int*)((_Float16*)Yv + row_g * H_N + c) = packed;
        }
      } else {
        const int d = d0 + crow;
        const int t = tp * RATE + (d >> 12);
        if (t < T_N) {
          const int b = d & (B_N - 1);
          ((float*)Yv)[((size_t)b * T_N + t) * H_N + c] = hv * maskF[b];
        }
      }
    }

#pragma unroll
    for (int kc = 0; kc < 4; ++kc) xc[kc] = xn[kc];
    __syncthreads();   // hs[nxt] complete before next step reads it
  }
}

// ---- launcher ----
extern "C" void kernel_launch(void* const* d_in, const int* in_sizes, int n_in,
                              void* d_out, int out_size, void* d_ws, size_t ws_size,
                              hipStream_t stream) {
  (void)in_sizes; (void)n_in; (void)out_size; (void)ws_size;
  const int*   tok = (const int*)d_in[0];
  const float* emb = (const float*)d_in[3];

  char* ws = (char*)d_ws;
  const size_t XBYTES = (size_t)212992 * H_N * 2;       // 54,525,952
  _Float16* X0    = (_Float16*)ws;
  _Float16* X1    = (_Float16*)(ws + XBYTES);
  _Float16* Wp    = (_Float16*)(ws + 2 * XBYTES);       // 3 x 98304 halves
  float*    biasP = (float*)(ws + 2 * XBYTES + 3 * 196608);
  float*    maskF = biasP + 3 * 512;

  for (int l = 0; l < 3; ++l) {
    const float* Wih = (const float*)d_in[4 + 4 * l];
    const float* Whh = (const float*)d_in[5 + 4 * l];
    const float* bih = (const float*)d_in[6 + 4 * l];
    const float* bhh = (const float*)d_in[7 + 4 * l];
    prep_weights_kernel<<<384, 128, 0, stream>>>(Wih, Whh, bih, bhh,
                                                 Wp + (size_t)l * 98304,
                                                 biasP + l * 512);
  }
  gather_kernel<<<12800, 256, 0, stream>>>(tok, emb, X0);
  mask_kernel<<<16, 256, 0, stream>>>(tok, maskF);
  // zero X0 pad rows [204800, 212992) — layer2's t=50,51 input padding
  hipMemsetAsync(X0 + (size_t)204800 * H_N, 0,
                 (size_t)(212992 - 204800) * H_N * 2, stream);

  // layer 0: rate 1, 50 steps, Bd=4096  : X0 -> X1 (fp16)
  gru_mfma_kernel<1, 50, false><<<256, 512, 0, stream>>>(
      X0, X1, Wp, biasP, maskF);
  // layer 1: rate 2, 25 steps, Bd=8192  : X1 -> X0 (fp16)
  gru_mfma_kernel<2, 25, false><<<512, 512, 0, stream>>>(
      X1, X0, Wp + 98304, biasP + 512, maskF);
  // layer 2: rate 4, 13 steps, Bd=16384 : X0 -> d_out (fp32, masked)
  gru_mfma_kernel<4, 13, true><<<1024, 512, 0, stream>>>(
      X0, (float*)d_out, Wp + 2 * 98304, biasP + 1024, maskF);
}